// Round 9
// baseline (74.891 us; speedup 1.0000x reference)
//
#include <hip/hip_runtime.h>
#include <hip/hip_bf16.h>

// out[b,t,u,c] = enc[b,t,:]·W[c,:512] + dec[b,u,:]·W[c,512:]
// B=4, T=256, U=64, D=512, C=1024. Output 256 MiB fp32 (write floor ~39us).
//
// K1 cvt:   fp32 -> bf16 + permute into MFMA-fragment order (1 KB wave-loads).
// K2 dec:   bf16-MFMA dec projection -> Pd (256x1024), fragment loads.
// K3 fused: block = 16 bt x 256 c (grid 4x64 = 256 blocks). Enc MFMA tile ->
//           LDS (16.5 KB), barrier, hoist enc slice to regs, then stream:
//           per u one 1 KB coalesced Pd read (L2) + four 1 KB CONTIGUOUS
//           nontemporal wave-stores (fill-shaped write pattern).

typedef float v4f   __attribute__((ext_vector_type(4)));
typedef float f32x4 __attribute__((ext_vector_type(4)));
typedef __attribute__((ext_vector_type(8))) short short8;

__device__ inline short bf16_of(float f) {
    __hip_bfloat16 h = __float2bfloat16(f);   // RNE
    return *reinterpret_cast<short*>(&h);
}

// ---------------- K1: fp32 -> bf16 fragment-layout permute -------------------
// One wave per 16x32 fragment block (1 KiB out). Wave-task ids:
//   [0,1024)    : enc  (64 mb x 16 kb)
//   [1024,1280) : dec  (16 mb x 16 kb)
//   [1280,2304) : Wenc (64 cb x 16 kb), W cols [0,512)
//   [2304,3328) : Wdec (64 cb x 16 kb), W cols [512,1024)
__global__ __launch_bounds__(256) void cvt_frag(
    const float* __restrict__ enc, const float* __restrict__ dec,
    const float* __restrict__ W,
    ushort* __restrict__ Xe_f, ushort* __restrict__ Xd_f,
    ushort* __restrict__ We_f, ushort* __restrict__ Wd_f)
{
    const int tid  = threadIdx.x;
    const int lane = tid & 63;
    const int l16  = lane & 15;
    const int kq   = lane >> 4;
    const int gid  = blockIdx.x * 4 + (tid >> 6);

    const float* src; ushort* dst; int g, rowStride, colOfs;
    if (gid < 1024)      { src = enc; dst = Xe_f; g = gid;        rowStride = 512;  colOfs = 0;   }
    else if (gid < 1280) { src = dec; dst = Xd_f; g = gid - 1024; rowStride = 512;  colOfs = 0;   }
    else if (gid < 2304) { src = W;   dst = We_f; g = gid - 1280; rowStride = 1024; colOfs = 0;   }
    else                 { src = W;   dst = Wd_f; g = gid - 2304; rowStride = 1024; colOfs = 512; }

    const int rb  = g >> 4;       // 16-row block
    const int kbi = g & 15;       // 32-k block
    const float* p = src + (size_t)(rb * 16 + l16) * rowStride + colOfs + kbi * 32 + kq * 8;
    float4 lo = *(const float4*)p;
    float4 hi = *(const float4*)(p + 4);
    short8 o;
    o[0] = bf16_of(lo.x); o[1] = bf16_of(lo.y); o[2] = bf16_of(lo.z); o[3] = bf16_of(lo.w);
    o[4] = bf16_of(hi.x); o[5] = bf16_of(hi.y); o[6] = bf16_of(hi.z); o[7] = bf16_of(hi.w);
    *(short8*)&dst[(size_t)g * 512 + lane * 8] = o;
}

// ---------------- K2: dec projection GEMM (fragment loads, split-K) ----------
// Grid (16 c-tiles, 16 m-tiles); block tile = 16(m) x 64(c); 4 waves.
__global__ __launch_bounds__(256) void dec_gemm_bf16(
    const ushort* __restrict__ Xd_f,  // frag layout (16 mb x 16 kb)
    const ushort* __restrict__ Wd_f,  // frag layout (64 cb x 16 kb)
    float* __restrict__ Pd)           // (256, 1024)
{
    const int tid  = threadIdx.x;
    const int wave = tid >> 6;
    const int lane = tid & 63;
    const int l16  = lane & 15;
    const int kq   = lane >> 4;

    const int kz = wave >> 1;
    const int wn = (wave & 1) * 32;
    const int mb = blockIdx.y;
    const int cBase = blockIdx.x * 64;
    const int cb0 = blockIdx.x * 4 + (wave & 1) * 2;

    const short8* xa  = (const short8*)Xd_f + (size_t)(mb  * 16 + kz * 8) * 64 + lane;
    const short8* wb0 = (const short8*)Wd_f + (size_t)(cb0       * 16 + kz * 8) * 64 + lane;
    const short8* wb1 = (const short8*)Wd_f + (size_t)((cb0 + 1) * 16 + kz * 8) * 64 + lane;

    f32x4 acc0 = {0.f,0.f,0.f,0.f}, acc1 = {0.f,0.f,0.f,0.f};
#pragma unroll
    for (int s = 0; s < 8; ++s) {
        short8 a  = xa [(size_t)s * 64];
        short8 b0 = wb0[(size_t)s * 64];
        short8 b1 = wb1[(size_t)s * 64];
        acc0 = __builtin_amdgcn_mfma_f32_16x16x32_bf16(a, b0, acc0, 0, 0, 0);
        acc1 = __builtin_amdgcn_mfma_f32_16x16x32_bf16(a, b1, acc1, 0, 0, 0);
    }

    __shared__ float Ps[16][65];
    if (kz == 1) {
#pragma unroll
        for (int r = 0; r < 4; ++r) {
            Ps[kq * 4 + r][wn + l16]      = acc0[r];
            Ps[kq * 4 + r][wn + 16 + l16] = acc1[r];
        }
    }
    __syncthreads();
    if (kz == 0) {
        float* p0 = Pd + (size_t)(mb * 16) * 1024 + cBase + wn;
#pragma unroll
        for (int r = 0; r < 4; ++r) {
            const int row = kq * 4 + r;
            p0[(size_t)row * 1024 + l16]      = acc0[r] + Ps[row][wn + l16];
            p0[(size_t)row * 1024 + 16 + l16] = acc1[r] + Ps[row][wn + 16 + l16];
        }
    }
}

// ---------------- K3: fused enc GEMM + fill-shaped broadcast stream ----------
// Grid (4 c-tiles, 64 bt-tiles), 256 threads = 4 waves. Block = 16 bt x 256 c.
// Wave w GEMMs cb columns w*4..w*4+3 (full K), then streams bt rows 4w..4w+3.
__global__ __launch_bounds__(256) void fused_enc_stream(
    const ushort* __restrict__ Xe_f,  // frag layout (64 mb x 16 kb)
    const ushort* __restrict__ We_f,  // frag layout (64 cb x 16 kb)
    const float* __restrict__ Pd,     // (256, 1024)
    float* __restrict__ out)          // (1024, 64, 1024)
{
    const int tid  = threadIdx.x;
    const int w    = tid >> 6;
    const int lane = tid & 63;
    const int l16  = lane & 15;
    const int kq   = lane >> 4;

    const int btBase = blockIdx.y * 16;
    const int cBase  = blockIdx.x * 256;
    const int b      = blockIdx.y >> 4;

    __shared__ float encS[16][264];     // 16.5 KiB; row pad vs bank hotspots

    // (1) Enc GEMM: 16 x 256 tile; wave w owns 4 cb columns, full K=512.
    {
        const short8* xa    = (const short8*)Xe_f + (size_t)(blockIdx.y * 16) * 64 + lane;
        const short8* wbase = (const short8*)We_f + lane;
        f32x4 acc[4] = {{0.f,0.f,0.f,0.f},{0.f,0.f,0.f,0.f},
                        {0.f,0.f,0.f,0.f},{0.f,0.f,0.f,0.f}};
#pragma unroll
        for (int s = 0; s < 16; ++s) {
            short8 a = xa[(size_t)s * 64];
#pragma unroll
            for (int j = 0; j < 4; ++j) {
                const int cb = blockIdx.x * 16 + w * 4 + j;
                short8 bf = wbase[(size_t)(cb * 16 + s) * 64];
                acc[j] = __builtin_amdgcn_mfma_f32_16x16x32_bf16(a, bf, acc[j], 0, 0, 0);
            }
        }
#pragma unroll
        for (int j = 0; j < 4; ++j)
#pragma unroll
            for (int r = 0; r < 4; ++r)      // D: col=l16, row=kq*4+r
                encS[kq * 4 + r][(w * 4 + j) * 16 + l16] = acc[j][r];
    }

    __syncthreads();

    // (2) Hoist this wave's 4 enc rows (c-slice lane*4) into registers.
    float4 e[4];
#pragma unroll
    for (int i = 0; i < 4; ++i)
        e[i] = *(const float4*)&encS[w * 4 + i][lane * 4];

    // (3) Stream: per u, one 1 KB coalesced Pd read + four 1 KB contiguous
    //     nontemporal wave-stores (rows btBase+4w..+3).
    const float* pd = Pd + (size_t)(b * 64) * 1024 + cBase + lane * 4;
    float*       po = out + (size_t)(btBase + w * 4) * 64 * 1024 + cBase + lane * 4;

#pragma unroll 8
    for (int u = 0; u < 64; ++u) {
        float4 d = *(const float4*)&pd[(size_t)u * 1024];
#pragma unroll
        for (int i = 0; i < 4; ++i) {
            v4f r = {e[i].x + d.x, e[i].y + d.y, e[i].z + d.z, e[i].w + d.w};
            __builtin_nontemporal_store(r, (v4f*)&po[((size_t)i * 64 + u) * 1024]);
        }
    }
}

extern "C" void kernel_launch(void* const* d_in, const int* in_sizes, int n_in,
                              void* d_out, int out_size, void* d_ws, size_t ws_size,
                              hipStream_t stream) {
    const float* enc = (const float*)d_in[0];   // (4,256,512)
    const float* dec = (const float*)d_in[1];   // (4,64,512)
    const float* W   = (const float*)d_in[2];   // (1024,1024)
    float* out = (float*)d_out;

    // Workspace: Pd 1 MiB | Xe_f 1 MiB | Xd_f 256 KiB | We_f 1 MiB | Wd_f 1 MiB
    char* ws = (char*)d_ws;
    float*  Pd   = (float*)(ws);
    ushort* Xe_f = (ushort*)(ws + (1u << 20));
    ushort* Xd_f = (ushort*)(ws + (2u << 20));
    ushort* We_f = (ushort*)(ws + (2u << 20) + (1u << 18));
    ushort* Wd_f = (ushort*)(ws + (3u << 20) + (1u << 18));

    cvt_frag<<<dim3(832), 256, 0, stream>>>(enc, dec, W, Xe_f, Xd_f, We_f, Wd_f);
    dec_gemm_bf16<<<dim3(16, 16), 256, 0, stream>>>(Xd_f, Wd_f, Pd);
    fused_enc_stream<<<dim3(4, 64), 256, 0, stream>>>(Xe_f, We_f, Pd, out);
}